// Round 11
// baseline (23991.496 us; speedup 1.0000x reference)
//
#include <hip/hip_runtime.h>

#define T_SEQ 8192
#define HDIM  2048
#define EDIM  2048
#define RBLK  64                      // recurrence blocks
#define ROWS_PER_BLK (HDIM / RBLK)    // 32 rows/block, 4 rows/wave

typedef unsigned long long u64;
typedef __attribute__((ext_vector_type(4))) unsigned int u32x4;
typedef __attribute__((ext_vector_type(4))) float f32x4;

// two 16B agent-coherent loads + full drain (fallback poll)
__device__ inline void poll_pair(const u64* p0, const u64* p1, u32x4& a, u32x4& b) {
    asm volatile("global_load_dwordx4 %0, %2, off sc1\n\t"
                 "global_load_dwordx4 %1, %3, off sc1\n\t"
                 "s_waitcnt vmcnt(0)"
                 : "=v"(a), "=v"(b) : "v"(p0), "v"(p1) : "memory");
}
// issue two 16B agent-coherent loads WITHOUT waiting
__device__ inline void issue2(const u64* p0, const u64* p1, u32x4& a, u32x4& b) {
    asm volatile("global_load_dwordx4 %0, %2, off sc1\n\t"
                 "global_load_dwordx4 %1, %3, off sc1"
                 : "=v"(a), "=v"(b) : "v"(p0), "v"(p1) : "memory");
}
// drain everything outstanding (ties a,b so checks order after)
__device__ inline void wait0(u32x4& x, u32x4& y) {
    asm volatile("s_waitcnt vmcnt(0)" : "+v"(x), "+v"(y) :: "memory");
}

// Non-rematerializable loads (results MUST live in registers)
__device__ inline f32x4 ld_w16(const float* p) {
    f32x4 r;
    asm volatile("global_load_dwordx4 %0, %1, off" : "=v"(r) : "v"(p));
    return r;
}
__device__ inline float ld_xp(const float* p) {
    float r;
    asm volatile("global_load_dword %0, %1, off" : "=v"(r) : "v"(p));
    return r;
}

// tanh via e^{2z}: clamp +-15, exp2, rcp (validated R8/R9: absmax unchanged)
__device__ inline float fast_tanh(float z) {
    float zc = fminf(fmaxf(z, -15.f), 15.f);
    float zs = zc * 2.88539008177792681f;   // 2*log2(e)
    float ez; asm("v_exp_f32 %0, %1" : "=v"(ez) : "v"(zs));
    float rc; float ezp = ez + 1.f;
    asm("v_rcp_f32 %0, %1" : "=v"(rc) : "v"(ezp));
    return (ez - 1.f) * rc;
}

// ---------------------------------------------------------------------------
// GEMM (NT): C[m][n] = sum_k A[m][k] * B[n][k] + bias[n]
// ---------------------------------------------------------------------------
__global__ __launch_bounds__(256) void gemm_nt_bias(
    const float* __restrict__ A, const float* __restrict__ B,
    const float* __restrict__ bias, float* __restrict__ C,
    int M, int N, int K)
{
    constexpr int BK = 32;
    __shared__ float As[BK][64 + 4];
    __shared__ float Bs[BK][64 + 4];

    const int tx = threadIdx.x & 15;
    const int ty = threadIdx.x >> 4;
    const int m0 = blockIdx.y * 64;
    const int n0 = blockIdx.x * 64;

    float acc[4][4] = {};

    for (int kk = 0; kk < K; kk += BK) {
        #pragma unroll
        for (int p = 0; p < 8; ++p) {
            int idx = p * 256 + threadIdx.x;
            int r = idx >> 5;
            int c = idx & 31;
            As[c][r] = A[(size_t)(m0 + r) * K + kk + c];
            Bs[c][r] = B[(size_t)(n0 + r) * K + kk + c];
        }
        __syncthreads();
        #pragma unroll
        for (int k = 0; k < BK; ++k) {
            float4 a = *(const float4*)&As[k][ty * 4];
            float4 b = *(const float4*)&Bs[k][tx * 4];
            float av[4] = {a.x, a.y, a.z, a.w};
            float bv[4] = {b.x, b.y, b.z, b.w};
            #pragma unroll
            for (int i = 0; i < 4; ++i)
                #pragma unroll
                for (int j = 0; j < 4; ++j)
                    acc[i][j] = fmaf(av[i], bv[j], acc[i][j]);
        }
        __syncthreads();
    }

    float4 bb = *(const float4*)&bias[n0 + tx * 4];
    float bvv[4] = {bb.x, bb.y, bb.z, bb.w};
    #pragma unroll
    for (int i = 0; i < 4; ++i) {
        float4 o;
        o.x = acc[i][0] + bvv[0];
        o.y = acc[i][1] + bvv[1];
        o.z = acc[i][2] + bvv[2];
        o.w = acc[i][3] + bvv[3];
        *(float4*)&C[(size_t)(m0 + ty * 4 + i) * N + n0 + tx * 4] = o;
    }
}

// ---------------------------------------------------------------------------
// Same GEMM, TRANSPOSED output: Ct[n][m] (xpT locality: 16 steps per line).
// ---------------------------------------------------------------------------
__global__ __launch_bounds__(256) void gemm_nt_bias_tc(
    const float* __restrict__ A, const float* __restrict__ B,
    const float* __restrict__ bias, float* __restrict__ Ct,
    int M, int N, int K)
{
    constexpr int BK = 32;
    __shared__ float As[BK][64 + 4];
    __shared__ float Bs[BK][64 + 4];

    const int tx = threadIdx.x & 15;
    const int ty = threadIdx.x >> 4;
    const int m0 = blockIdx.y * 64;
    const int n0 = blockIdx.x * 64;

    float acc[4][4] = {};

    for (int kk = 0; kk < K; kk += BK) {
        #pragma unroll
        for (int p = 0; p < 8; ++p) {
            int idx = p * 256 + threadIdx.x;
            int r = idx >> 5;
            int c = idx & 31;
            As[c][r] = A[(size_t)(m0 + r) * K + kk + c];
            Bs[c][r] = B[(size_t)(n0 + r) * K + kk + c];
        }
        __syncthreads();
        #pragma unroll
        for (int k = 0; k < BK; ++k) {
            float4 a = *(const float4*)&As[k][ty * 4];
            float4 b = *(const float4*)&Bs[k][tx * 4];
            float av[4] = {a.x, a.y, a.z, a.w};
            float bv[4] = {b.x, b.y, b.z, b.w};
            #pragma unroll
            for (int i = 0; i < 4; ++i)
                #pragma unroll
                for (int j = 0; j < 4; ++j)
                    acc[i][j] = fmaf(av[i], bv[j], acc[i][j]);
        }
        __syncthreads();
    }

    float4 bb = *(const float4*)&bias[n0 + tx * 4];
    float bvv[4] = {bb.x, bb.y, bb.z, bb.w};
    #pragma unroll
    for (int j = 0; j < 4; ++j) {
        float4 o;
        o.x = acc[0][j] + bvv[j];
        o.y = acc[1][j] + bvv[j];
        o.z = acc[2][j] + bvv[j];
        o.w = acc[3][j] + bvv[j];
        *(float4*)&Ct[(size_t)(n0 + tx * 4 + j) * M + m0 + ty * 4] = o;
    }
}

// ---------------------------------------------------------------------------
// Recurrence (R9 structure + carried-poll: polls/xq for step t+1 are ISSUED
// immediately after step t's tagged stores, so the top-of-loop vmcnt(0)
// drains store-ack, poll RTT and xq in PARALLEL instead of serially (vmcnt
// is in-order and counts stores — R9 paid store-ack THEN poll RTT).
// 64 blocks x 512 threads; wave w owns rows b*32+w*4..+3; W_h in 128
// asm-loaded VGPRs/lane. Sync: hbuf[2][HDIM] u64 (tag<<32|f32bits), plain
// relaxed agent-scope stores; own-row polls issued after own stores (same
// address order; fallback loop self-corrects if fabric reorders).
// Overwrite safety unchanged: a wave's tag-t store value-depends on all its
// step-(t-1) poll results, and poll success requires all 2048 tag-t words.
// ---------------------------------------------------------------------------
__global__ __launch_bounds__(512, 1) void rnn_recurrence(
    const float* __restrict__ Wh, const float* __restrict__ xpT,
    float* __restrict__ Hs, u64* __restrict__ hbuf, int T)
{
    const int tid  = threadIdx.x;
    const int lane = tid & 63;
    const int wid  = tid >> 6;                              // 0..7
    const int r0   = blockIdx.x * ROWS_PER_BLK + wid * 4;   // wave's first row

    const float* wr0 = Wh + (size_t)(r0 + 0) * HDIM + lane * 4;
    const float* wr1 = Wh + (size_t)(r0 + 1) * HDIM + lane * 4;
    const float* wr2 = Wh + (size_t)(r0 + 2) * HDIM + lane * 4;
    const float* wr3 = Wh + (size_t)(r0 + 3) * HDIM + lane * 4;

    // 32 asm-loaded float4 = 128 VGPRs of W_h, register-resident (non-remat)
    f32x4 w00 = ld_w16(wr0 + 0*256), w01 = ld_w16(wr0 + 1*256), w02 = ld_w16(wr0 + 2*256), w03 = ld_w16(wr0 + 3*256);
    f32x4 w04 = ld_w16(wr0 + 4*256), w05 = ld_w16(wr0 + 5*256), w06 = ld_w16(wr0 + 6*256), w07 = ld_w16(wr0 + 7*256);
    f32x4 w10 = ld_w16(wr1 + 0*256), w11 = ld_w16(wr1 + 1*256), w12 = ld_w16(wr1 + 2*256), w13 = ld_w16(wr1 + 3*256);
    f32x4 w14 = ld_w16(wr1 + 4*256), w15 = ld_w16(wr1 + 5*256), w16 = ld_w16(wr1 + 6*256), w17 = ld_w16(wr1 + 7*256);
    f32x4 w20 = ld_w16(wr2 + 0*256), w21 = ld_w16(wr2 + 1*256), w22 = ld_w16(wr2 + 2*256), w23 = ld_w16(wr2 + 3*256);
    f32x4 w24 = ld_w16(wr2 + 4*256), w25 = ld_w16(wr2 + 5*256), w26 = ld_w16(wr2 + 6*256), w27 = ld_w16(wr2 + 7*256);
    f32x4 w30 = ld_w16(wr3 + 0*256), w31 = ld_w16(wr3 + 1*256), w32 = ld_w16(wr3 + 2*256), w33 = ld_w16(wr3 + 3*256);
    f32x4 w34 = ld_w16(wr3 + 4*256), w35 = ld_w16(wr3 + 5*256), w36 = ld_w16(wr3 + 6*256), w37 = ld_w16(wr3 + 7*256);
    asm volatile("s_waitcnt vmcnt(0)" ::: "memory");

    __shared__ float hsm[HDIM];

    // per-lane xp row pointer: lane l reads row r0+(l&3) (post-fold mapping)
    const float* xq_base = xpT + (size_t)(r0 + (lane & 3)) * T;

    u32x4 a, b;      // carried in-flight poll results
    float xq;        // carried in-flight xp for current step

    // ---- t = 0: h1 = tanh(xp[0]); store; issue polls+xq for t=1 ----
    {
        float xq0 = xq_base[0];
        float hn = fast_tanh(xq0);
        if (lane < 4) {
            u64 pk = ((u64)1u << 32) | (u64)__float_as_uint(hn);
            __hip_atomic_store(&hbuf[(size_t)1 * HDIM + r0 + lane], pk,
                               __ATOMIC_RELAXED, __HIP_MEMORY_SCOPE_AGENT);
            Hs[r0 + lane] = hn;
        }
        const u64* hbn = hbuf + (size_t)1 * HDIM;
        issue2(hbn + 2 * tid, hbn + 1024 + 2 * tid, a, b);
        xq = ld_xp(xq_base + 1);
    }

    for (int t = 1; t < T; ++t) {
        // drain: prev stores' ack || polls || xq — all in parallel
        wait0(a, b);
        const unsigned tg = (unsigned)t;
        if ((a.y != tg) | (a.w != tg) | (b.y != tg) | (b.w != tg)) {
            const u64* hb = hbuf + (size_t)(t & 1) * HDIM;
            const u64* p0 = hb + 2 * tid;
            const u64* p1 = hb + 1024 + 2 * tid;
            do { poll_pair(p0, p1, a, b); }
            while ((a.y != tg) | (a.w != tg) | (b.y != tg) | (b.w != tg));
        }

        ((float2*)hsm)[tid] =
            make_float2(__uint_as_float(a.x), __uint_as_float(a.z));
        ((float2*)hsm)[tid + 512] =
            make_float2(__uint_as_float(b.x), __uint_as_float(b.z));
        __syncthreads();

        float s0 = 0.f, s1 = 0.f, s2 = 0.f, s3 = 0.f;
        #define RNN_STEP(IDX, WA, WB, WC, WD)                                   \
        {   float4 h4 = ((const float4*)hsm)[(IDX) * 64 + lane];                \
            s0 = fmaf(WA.x, h4.x, s0); s0 = fmaf(WA.y, h4.y, s0);               \
            s0 = fmaf(WA.z, h4.z, s0); s0 = fmaf(WA.w, h4.w, s0);               \
            s1 = fmaf(WB.x, h4.x, s1); s1 = fmaf(WB.y, h4.y, s1);               \
            s1 = fmaf(WB.z, h4.z, s1); s1 = fmaf(WB.w, h4.w, s1);               \
            s2 = fmaf(WC.x, h4.x, s2); s2 = fmaf(WC.y, h4.y, s2);               \
            s2 = fmaf(WC.z, h4.z, s2); s2 = fmaf(WC.w, h4.w, s2);               \
            s3 = fmaf(WD.x, h4.x, s3); s3 = fmaf(WD.y, h4.y, s3);               \
            s3 = fmaf(WD.z, h4.z, s3); s3 = fmaf(WD.w, h4.w, s3); }
        RNN_STEP(0, w00, w10, w20, w30)
        RNN_STEP(1, w01, w11, w21, w31)
        RNN_STEP(2, w02, w12, w22, w32)
        RNN_STEP(3, w03, w13, w23, w33)
        RNN_STEP(4, w04, w14, w24, w34)
        RNN_STEP(5, w05, w15, w25, w35)
        RNN_STEP(6, w06, w16, w26, w36)
        RNN_STEP(7, w07, w17, w27, w37)
        #undef RNN_STEP

        // 4-chain fold: 8 shfl total, lane l ends with row (l&3)'s sum.
        float fa = (lane & 1) ? s1 : s0;
        float fb = (lane & 1) ? s0 : s1;
        fa += __shfl_xor(fb, 1);
        float fc = (lane & 1) ? s3 : s2;
        float fd = (lane & 1) ? s2 : s3;
        fc += __shfl_xor(fd, 1);
        float fe = (lane & 2) ? fc : fa;
        float ff = (lane & 2) ? fa : fc;
        fe += __shfl_xor(ff, 2);
        #pragma unroll
        for (int off = 4; off < 64; off <<= 1) fe += __shfl_xor(fe, off);

        float hn = fast_tanh(fe + xq);

        if (lane < 4) {
            u64 pk = ((u64)(unsigned)(t + 1) << 32) | (u64)__float_as_uint(hn);
            __hip_atomic_store(&hbuf[(size_t)((t + 1) & 1) * HDIM + r0 + lane], pk,
                               __ATOMIC_RELAXED, __HIP_MEMORY_SCOPE_AGENT);
            Hs[(size_t)t * HDIM + r0 + lane] = hn;
        }
        // issue next step's polls + xq NOW (in flight across loop back-edge;
        // drained by next iteration's wait0 in parallel with store acks)
        const u64* hbn = hbuf + (size_t)((t + 1) & 1) * HDIM;
        issue2(hbn + 2 * tid, hbn + 1024 + 2 * tid, a, b);
        int tn = (t + 1 < T) ? t + 1 : T - 1;
        xq = ld_xp(xq_base + tn);
    }
}

// ---------------------------------------------------------------------------
// Row softmax over EDIM=2048: one block (256 threads) per row.
// ---------------------------------------------------------------------------
__global__ __launch_bounds__(256) void softmax_rows(
    const float* __restrict__ logits, float* __restrict__ out)
{
    const int row = blockIdx.x;
    const float4* in4 = (const float4*)(logits + (size_t)row * EDIM);
    float4* out4 = (float4*)(out + (size_t)row * EDIM);

    float4 v0 = in4[threadIdx.x];
    float4 v1 = in4[threadIdx.x + 256];

    float m = fmaxf(fmaxf(fmaxf(v0.x, v0.y), fmaxf(v0.z, v0.w)),
                    fmaxf(fmaxf(v1.x, v1.y), fmaxf(v1.z, v1.w)));
    #pragma unroll
    for (int off = 32; off > 0; off >>= 1) m = fmaxf(m, __shfl_xor(m, off));

    __shared__ float red[4];
    if ((threadIdx.x & 63) == 0) red[threadIdx.x >> 6] = m;
    __syncthreads();
    m = fmaxf(fmaxf(red[0], red[1]), fmaxf(red[2], red[3]));
    __syncthreads();

    float e[8];
    e[0] = expf(v0.x - m); e[1] = expf(v0.y - m);
    e[2] = expf(v0.z - m); e[3] = expf(v0.w - m);
    e[4] = expf(v1.x - m); e[5] = expf(v1.y - m);
    e[6] = expf(v1.z - m); e[7] = expf(v1.w - m);

    float s = e[0] + e[1] + e[2] + e[3] + e[4] + e[5] + e[6] + e[7];
    #pragma unroll
    for (int off = 32; off > 0; off >>= 1) s += __shfl_xor(s, off);
    if ((threadIdx.x & 63) == 0) red[threadIdx.x >> 6] = s;
    __syncthreads();
    s = red[0] + red[1] + red[2] + red[3];

    float inv = 1.0f / s;
    out4[threadIdx.x]       = make_float4(e[0] * inv, e[1] * inv, e[2] * inv, e[3] * inv);
    out4[threadIdx.x + 256] = make_float4(e[4] * inv, e[5] * inv, e[6] * inv, e[7] * inv);
}

__global__ void copy_vec(const float* __restrict__ src, float* __restrict__ dst, int n)
{
    int i = blockIdx.x * blockDim.x + threadIdx.x;
    if (i < n) dst[i] = src[i];
}

// ---------------------------------------------------------------------------
extern "C" void kernel_launch(void* const* d_in, const int* in_sizes, int n_in,
                              void* d_out, int out_size, void* d_ws, size_t ws_size,
                              hipStream_t stream)
{
    const float* x  = (const float*)d_in[0];   // [T_SEQ][EDIM]
    const float* Wh = (const float*)d_in[1];   // [HDIM][HDIM]
    const float* Wx = (const float*)d_in[2];   // [HDIM][EDIM]
    const float* Wy = (const float*)d_in[3];   // [EDIM][HDIM]
    const float* Bh = (const float*)d_in[4];   // [HDIM]
    const float* By = (const float*)d_in[5];   // [EDIM]

    float* out    = (float*)d_out;
    float* hfinal = out;                 // [HDIM]
    float* hs     = out + HDIM;          // [T_SEQ][HDIM]: holds hs, then probs

    float* xpT  = (float*)d_ws;                                   // [HDIM][T_SEQ]
    u64*   hbuf = (u64*)((char*)d_ws + (size_t)T_SEQ * HDIM * 4); // [2][HDIM]
    float* logits = xpT;                 // reuse (xpT dead after recurrence)

    // clear tagged h buffers so replays never see stale tags
    hipMemsetAsync(hbuf, 0, 2 * HDIM * sizeof(u64), stream);

    // Phase 1: xpT = (x @ Wx^T + Bh)^T   -> [HDIM][T_SEQ]
    gemm_nt_bias_tc<<<dim3(HDIM / 64, T_SEQ / 64), 256, 0, stream>>>(
        x, Wx, Bh, xpT, T_SEQ, HDIM, EDIM);

    // Phase 2: recurrence — cooperative launch only to guarantee co-residency
    int T = T_SEQ;
    const float* xpT_c = xpT;
    void* args[] = {(void*)&Wh, (void*)&xpT_c, (void*)&hs, (void*)&hbuf, (void*)&T};
    hipLaunchCooperativeKernel((void*)rnn_recurrence, dim3(RBLK), dim3(512),
                               args, 0, stream);

    // Phase 3: logits = hs @ Wy^T + By   (normal [T][E] layout)
    gemm_nt_bias<<<dim3(EDIM / 64, T_SEQ / 64), 256, 0, stream>>>(
        hs, Wy, By, logits, T_SEQ, EDIM, HDIM);

    // Phase 4: h_final = hs[T-1] (before softmax overwrites hs region)
    copy_vec<<<dim3(HDIM / 256), 256, 0, stream>>>(
        hs + (size_t)(T_SEQ - 1) * HDIM, hfinal, HDIM);

    // Phase 5: softmax rows: logits (ws) -> output region of d_out
    softmax_rows<<<dim3(T_SEQ), 256, 0, stream>>>(logits, hs);
}

// Round 12
// 22464.844 us; speedup vs baseline: 1.0680x; 1.0680x over previous
//
#include <hip/hip_runtime.h>

#define T_SEQ 8192
#define HDIM  2048
#define EDIM  2048
#define RBLK  64                      // recurrence blocks
#define NWORK 192                     // GEMM worker blocks
#define ROWS_PER_BLK (HDIM / RBLK)    // 32 rows/block, 4 rows/wave

typedef unsigned long long u64;
typedef unsigned int u32;
typedef __attribute__((ext_vector_type(4))) unsigned int u32x4;
typedef __attribute__((ext_vector_type(4))) float f32x4;
typedef __attribute__((ext_vector_type(2))) float f32x2;

// two 16B agent-coherent loads + full drain (R9 proven poll)
__device__ inline void poll_pair(const u64* p0, const u64* p1, u32x4& a, u32x4& b) {
    asm volatile("global_load_dwordx4 %0, %2, off sc1\n\t"
                 "global_load_dwordx4 %1, %3, off sc1\n\t"
                 "s_waitcnt vmcnt(0)"
                 : "=v"(a), "=v"(b) : "v"(p0), "v"(p1) : "memory");
}
__device__ inline f32x4 ld_w16(const float* p) {
    f32x4 r;
    asm volatile("global_load_dwordx4 %0, %1, off" : "=v"(r) : "v"(p));
    return r;
}
__device__ inline u32 ld_u32_sc1(const u32* p) {
    u32 r;
    asm volatile("global_load_dword %0, %1, off sc1\n\ts_waitcnt vmcnt(0)"
                 : "=v"(r) : "v"(p) : "memory");
    return r;
}
__device__ inline void st_u32_sc1(u32* p, u32 v) {
    asm volatile("global_store_dword %0, %1, off sc1" :: "v"(p), "v"(v) : "memory");
}
__device__ inline void st8_sc1(float* p, f32x2 v) {
    asm volatile("global_store_dwordx2 %0, %1, off sc1" :: "v"(p), "v"(v) : "memory");
}

// tanh via e^{2z}: clamp +-15, exp2, rcp (validated R8/R9: absmax unchanged)
__device__ inline float fast_tanh(float z) {
    float zc = fminf(fmaxf(z, -15.f), 15.f);
    float zs = zc * 2.88539008177792681f;   // 2*log2(e)
    float ez; asm("v_exp_f32 %0, %1" : "=v"(ez) : "v"(zs));
    float rc; float ezp = ez + 1.f;
    asm("v_rcp_f32 %0, %1" : "=v"(rc) : "v"(ezp));
    return (ez - 1.f) * rc;
}

// ---------------------------------------------------------------------------
// FUSED cooperative kernel: blocks 0..63 run the R9 recurrence (unchanged
// sync structure); blocks 64..255 are GEMM workers that produce xpT ahead of
// the recurrence (paced <=8 t-columns ahead via pub) and, if fuse3, consume
// hs into logits as soon as rows are provably visible.
//
// Visibility rules used:
//  - xp gate: cnt[c]==32 => all 32 tiles of t-column c stored (sc1, drained
//    before the atomicAdd) => L3 has them; reader caches were invalidated at
//    dispatch start and first-touch after the gate.
//  - hs gate: block b stores tag t+1 only after its iter-t vmcnt(0) drained
//    Hs[t-1]; block0 publishes pub=t after seeing ALL tag-t => Hs[<=t-2]
//    globally visible. GEMM-3 m-tile waits pub >= m0+65 (last tile: done==64,
//    each recurrence block signals done after a final vmcnt(0)+barrier).
// ---------------------------------------------------------------------------
__global__ __launch_bounds__(512, 2) void rnn_fused(
    const float* __restrict__ x,  const float* __restrict__ Wh,
    const float* __restrict__ Wx, const float* __restrict__ Wy,
    const float* __restrict__ Bh, const float* __restrict__ By,
    float* __restrict__ xpT, float* __restrict__ Hs, u64* __restrict__ hbuf,
    u32* __restrict__ cnt, u32* __restrict__ pub, u32* __restrict__ done,
    float* __restrict__ lbuf, int fuse3)
{
    __shared__ union {
        float hsm[HDIM];                               // recurrence path
        struct { float As[32][68]; float Bs[32][68]; } g;  // worker path
    } sm;

    const int tid = threadIdx.x;

    if (blockIdx.x < RBLK) {
        // ================= RECURRENCE (R9, unchanged core) =================
        const int lane = tid & 63;
        const int wid  = tid >> 6;
        const int r0   = blockIdx.x * ROWS_PER_BLK + wid * 4;

        const float* wr0 = Wh + (size_t)(r0 + 0) * HDIM + lane * 4;
        const float* wr1 = Wh + (size_t)(r0 + 1) * HDIM + lane * 4;
        const float* wr2 = Wh + (size_t)(r0 + 2) * HDIM + lane * 4;
        const float* wr3 = Wh + (size_t)(r0 + 3) * HDIM + lane * 4;

        f32x4 w00 = ld_w16(wr0 + 0*256), w01 = ld_w16(wr0 + 1*256), w02 = ld_w16(wr0 + 2*256), w03 = ld_w16(wr0 + 3*256);
        f32x4 w04 = ld_w16(wr0 + 4*256), w05 = ld_w16(wr0 + 5*256), w06 = ld_w16(wr0 + 6*256), w07 = ld_w16(wr0 + 7*256);
        f32x4 w10 = ld_w16(wr1 + 0*256), w11 = ld_w16(wr1 + 1*256), w12 = ld_w16(wr1 + 2*256), w13 = ld_w16(wr1 + 3*256);
        f32x4 w14 = ld_w16(wr1 + 4*256), w15 = ld_w16(wr1 + 5*256), w16 = ld_w16(wr1 + 6*256), w17 = ld_w16(wr1 + 7*256);
        f32x4 w20 = ld_w16(wr2 + 0*256), w21 = ld_w16(wr2 + 1*256), w22 = ld_w16(wr2 + 2*256), w23 = ld_w16(wr2 + 3*256);
        f32x4 w24 = ld_w16(wr2 + 4*256), w25 = ld_w16(wr2 + 5*256), w26 = ld_w16(wr2 + 6*256), w27 = ld_w16(wr2 + 7*256);
        f32x4 w30 = ld_w16(wr3 + 0*256), w31 = ld_w16(wr3 + 1*256), w32 = ld_w16(wr3 + 2*256), w33 = ld_w16(wr3 + 3*256);
        f32x4 w34 = ld_w16(wr3 + 4*256), w35 = ld_w16(wr3 + 5*256), w36 = ld_w16(wr3 + 6*256), w37 = ld_w16(wr3 + 7*256);
        asm volatile("s_waitcnt vmcnt(0)" ::: "memory");

        for (int t = 0; t < T_SEQ; ++t) {
            // gate: xp t-column ready (one check per 64 steps; spins only at startup)
            if ((t & 63) == 0) {
                const u32 c = (u32)(t >> 6);
                while (ld_u32_sc1(&cnt[c]) != 32u) __builtin_amdgcn_s_sleep(8);
            }
            float xq = 0.f;
            if (lane < 4) xq = xpT[(size_t)(r0 + lane) * T_SEQ + t];

            float sv = 0.f;
            if (t > 0) {
                const u64* hb = hbuf + (size_t)(t & 1) * HDIM;
                const unsigned tg = (unsigned)t;
                const u64* p0 = hb + 2 * tid;
                const u64* p1 = hb + 1024 + 2 * tid;

                u32x4 a, b;
                poll_pair(p0, p1, a, b);
                while ((a.y != tg) | (a.w != tg) | (b.y != tg) | (b.w != tg))
                    poll_pair(p0, p1, a, b);

                if (blockIdx.x == 0 && tid == 0) st_u32_sc1(pub, (u32)t);

                ((float2*)sm.hsm)[tid] =
                    make_float2(__uint_as_float(a.x), __uint_as_float(a.z));
                ((float2*)sm.hsm)[tid + 512] =
                    make_float2(__uint_as_float(b.x), __uint_as_float(b.z));
                __syncthreads();

                float s0 = 0.f, s1 = 0.f, s2 = 0.f, s3 = 0.f;
                #define RNN_STEP(IDX, WA, WB, WC, WD)                                   \
                {   float4 h4 = ((const float4*)sm.hsm)[(IDX) * 64 + lane];             \
                    s0 = fmaf(WA.x, h4.x, s0); s0 = fmaf(WA.y, h4.y, s0);               \
                    s0 = fmaf(WA.z, h4.z, s0); s0 = fmaf(WA.w, h4.w, s0);               \
                    s1 = fmaf(WB.x, h4.x, s1); s1 = fmaf(WB.y, h4.y, s1);               \
                    s1 = fmaf(WB.z, h4.z, s1); s1 = fmaf(WB.w, h4.w, s1);               \
                    s2 = fmaf(WC.x, h4.x, s2); s2 = fmaf(WC.y, h4.y, s2);               \
                    s2 = fmaf(WC.z, h4.z, s2); s2 = fmaf(WC.w, h4.w, s2);               \
                    s3 = fmaf(WD.x, h4.x, s3); s3 = fmaf(WD.y, h4.y, s3);               \
                    s3 = fmaf(WD.z, h4.z, s3); s3 = fmaf(WD.w, h4.w, s3); }
                RNN_STEP(0, w00, w10, w20, w30)
                RNN_STEP(1, w01, w11, w21, w31)
                RNN_STEP(2, w02, w12, w22, w32)
                RNN_STEP(3, w03, w13, w23, w33)
                RNN_STEP(4, w04, w14, w24, w34)
                RNN_STEP(5, w05, w15, w25, w35)
                RNN_STEP(6, w06, w16, w26, w36)
                RNN_STEP(7, w07, w17, w27, w37)
                #undef RNN_STEP

                float fa = (lane & 1) ? s1 : s0;
                float fb = (lane & 1) ? s0 : s1;
                fa += __shfl_xor(fb, 1);
                float fc = (lane & 1) ? s3 : s2;
                float fd = (lane & 1) ? s2 : s3;
                fc += __shfl_xor(fd, 1);
                float fe = (lane & 2) ? fc : fa;
                float ff = (lane & 2) ? fa : fc;
                fe += __shfl_xor(ff, 2);
                #pragma unroll
                for (int off = 4; off < 64; off <<= 1) fe += __shfl_xor(fe, off);
                sv = fe;
            }

            if (lane < 4) {
                float hn = fast_tanh(sv + xq);
                u64 pk = ((u64)(unsigned)(t + 1) << 32) | (u64)__float_as_uint(hn);
                __hip_atomic_store(&hbuf[(size_t)((t + 1) & 1) * HDIM + r0 + lane], pk,
                                   __ATOMIC_RELAXED, __HIP_MEMORY_SCOPE_AGENT);
                __hip_atomic_store(&Hs[(size_t)t * HDIM + r0 + lane], hn,
                                   __ATOMIC_RELAXED, __HIP_MEMORY_SCOPE_AGENT);
            }
        }
        // final: prove Hs fully visible, then signal done
        asm volatile("s_waitcnt vmcnt(0)" ::: "memory");
        __syncthreads();
        if (tid == 0) atomicAdd(done, 1u);

    } else {
        // ========================= GEMM WORKERS =========================
        const int wblk = blockIdx.x - RBLK;
        const int ty = tid >> 4, tx = tid & 15;
        const int ty2 = ty * 2, tx4 = tx * 4;

        // ---- GEMM-1: xpT[n][m] = (x @ Wx^T + Bh)^T, t-column-major order ----
        for (int i = wblk; i < (T_SEQ / 64) * (HDIM / 64); i += NWORK) {
            const int tcol = i >> 5;           // t-tile index (m0 = tcol*64)
            const int nrow = i & 31;           // h-tile index
            if (tcol > 8) {                    // pace: <=8 columns ahead
                const u32 needp = (u32)((tcol - 8) * 64);
                if (tid == 0)
                    while (ld_u32_sc1(pub) < needp) __builtin_amdgcn_s_sleep(32);
                __syncthreads();
            }
            const int m0 = tcol * 64, n0 = nrow * 64;

            float a00 = 0.f, a01 = 0.f, a02 = 0.f, a03 = 0.f;
            float a10 = 0.f, a11 = 0.f, a12 = 0.f, a13 = 0.f;
            for (int kk = 0; kk < EDIM; kk += 32) {
                #pragma unroll
                for (int p = 0; p < 4; ++p) {
                    int idx = p * 512 + tid;
                    int r = idx >> 5, c = idx & 31;
                    sm.g.As[c][r] = x [(size_t)(m0 + r) * EDIM + kk + c];
                    sm.g.Bs[c][r] = Wx[(size_t)(n0 + r) * EDIM + kk + c];
                }
                __syncthreads();
                #pragma unroll
                for (int k = 0; k < 32; ++k) {
                    const float q0 = sm.g.As[k][ty2], q1 = sm.g.As[k][ty2 + 1];
                    const float4 b = *(const float4*)&sm.g.Bs[k][tx4];
                    a00 = fmaf(q0, b.x, a00); a01 = fmaf(q0, b.y, a01);
                    a02 = fmaf(q0, b.z, a02); a03 = fmaf(q0, b.w, a03);
                    a10 = fmaf(q1, b.x, a10); a11 = fmaf(q1, b.y, a11);
                    a12 = fmaf(q1, b.z, a12); a13 = fmaf(q1, b.w, a13);
                }
                __syncthreads();
            }
            {
                float accr[2][4] = {{a00,a01,a02,a03},{a10,a11,a12,a13}};
                #pragma unroll
                for (int j = 0; j < 4; ++j) {
                    float bb = Bh[n0 + tx4 + j];
                    f32x2 v; v.x = accr[0][j] + bb; v.y = accr[1][j] + bb;
                    st8_sc1(&xpT[(size_t)(n0 + tx4 + j) * T_SEQ + m0 + ty2], v);
                }
            }
            asm volatile("s_waitcnt vmcnt(0)" ::: "memory");
            __syncthreads();
            if (tid == 0) atomicAdd(&cnt[tcol], 1u);
        }

        // ---- GEMM-3: lbuf[t][e] = hs @ Wy^T + By, gated on hs visibility ----
        if (fuse3) {
            for (int i = wblk; i < (T_SEQ / 64) * (EDIM / 64); i += NWORK) {
                const int mrow = i >> 5, ncol = i & 31;
                const int m0 = mrow * 64, n0 = ncol * 64;
                const u32 needp = (u32)(m0 + 65);
                if (tid == 0) {
                    if (needp <= (u32)(T_SEQ - 1)) {
                        while (ld_u32_sc1(pub) < needp) __builtin_amdgcn_s_sleep(32);
                    } else {
                        while (ld_u32_sc1(done) < (u32)RBLK) __builtin_amdgcn_s_sleep(32);
                    }
                }
                __syncthreads();

                float a00 = 0.f, a01 = 0.f, a02 = 0.f, a03 = 0.f;
                float a10 = 0.f, a11 = 0.f, a12 = 0.f, a13 = 0.f;
                for (int kk = 0; kk < HDIM; kk += 32) {
                    #pragma unroll
                    for (int p = 0; p < 4; ++p) {
                        int idx = p * 512 + tid;
                        int r = idx >> 5, c = idx & 31;
                        sm.g.As[c][r] = Hs[(size_t)(m0 + r) * HDIM + kk + c];
                        sm.g.Bs[c][r] = Wy[(size_t)(n0 + r) * HDIM + kk + c];
                    }
                    __syncthreads();
                    #pragma unroll
                    for (int k = 0; k < 32; ++k) {
                        const float q0 = sm.g.As[k][ty2], q1 = sm.g.As[k][ty2 + 1];
                        const float4 b = *(const float4*)&sm.g.Bs[k][tx4];
                        a00 = fmaf(q0, b.x, a00); a01 = fmaf(q0, b.y, a01);
                        a02 = fmaf(q0, b.z, a02); a03 = fmaf(q0, b.w, a03);
                        a10 = fmaf(q1, b.x, a10); a11 = fmaf(q1, b.y, a11);
                        a12 = fmaf(q1, b.z, a12); a13 = fmaf(q1, b.w, a13);
                    }
                    __syncthreads();
                }
                {
                    float accr[2][4] = {{a00,a01,a02,a03},{a10,a11,a12,a13}};
                    #pragma unroll
                    for (int r = 0; r < 2; ++r) {
                        float4 o;
                        o.x = accr[r][0] + By[n0 + tx4 + 0];
                        o.y = accr[r][1] + By[n0 + tx4 + 1];
                        o.z = accr[r][2] + By[n0 + tx4 + 2];
                        o.w = accr[r][3] + By[n0 + tx4 + 3];
                        *(float4*)&lbuf[(size_t)(m0 + ty2 + r) * EDIM + n0 + tx4] = o;
                    }
                }
            }
        }
    }
}

// ---------------------------------------------------------------------------
// Fallback host GEMM (NT): C[m][n] = sum_k A[m][k]*B[n][k] + bias[n]
// ---------------------------------------------------------------------------
__global__ __launch_bounds__(256) void gemm_nt_bias(
    const float* __restrict__ A, const float* __restrict__ B,
    const float* __restrict__ bias, float* __restrict__ C,
    int M, int N, int K)
{
    constexpr int BK = 32;
    __shared__ float As[BK][64 + 4];
    __shared__ float Bs[BK][64 + 4];

    const int tx = threadIdx.x & 15;
    const int ty = threadIdx.x >> 4;
    const int m0 = blockIdx.y * 64;
    const int n0 = blockIdx.x * 64;

    float acc[4][4] = {};
    for (int kk = 0; kk < K; kk += BK) {
        #pragma unroll
        for (int p = 0; p < 8; ++p) {
            int idx = p * 256 + threadIdx.x;
            int r = idx >> 5, c = idx & 31;
            As[c][r] = A[(size_t)(m0 + r) * K + kk + c];
            Bs[c][r] = B[(size_t)(n0 + r) * K + kk + c];
        }
        __syncthreads();
        #pragma unroll
        for (int k = 0; k < BK; ++k) {
            float4 a = *(const float4*)&As[k][ty * 4];
            float4 b = *(const float4*)&Bs[k][tx * 4];
            float av[4] = {a.x, a.y, a.z, a.w};
            float bv[4] = {b.x, b.y, b.z, b.w};
            #pragma unroll
            for (int i = 0; i < 4; ++i)
                #pragma unroll
                for (int j = 0; j < 4; ++j)
                    acc[i][j] = fmaf(av[i], bv[j], acc[i][j]);
        }
        __syncthreads();
    }
    float4 bb = *(const float4*)&bias[n0 + tx * 4];
    float bvv[4] = {bb.x, bb.y, bb.z, bb.w};
    #pragma unroll
    for (int i = 0; i < 4; ++i) {
        float4 o;
        o.x = acc[i][0] + bvv[0];
        o.y = acc[i][1] + bvv[1];
        o.z = acc[i][2] + bvv[2];
        o.w = acc[i][3] + bvv[3];
        *(float4*)&C[(size_t)(m0 + ty * 4 + i) * N + n0 + tx * 4] = o;
    }
}

// ---------------------------------------------------------------------------
__global__ __launch_bounds__(256) void softmax_rows(
    const float* __restrict__ logits, float* __restrict__ out)
{
    const int row = blockIdx.x;
    const float4* in4 = (const float4*)(logits + (size_t)row * EDIM);
    float4* out4 = (float4*)(out + (size_t)row * EDIM);

    float4 v0 = in4[threadIdx.x];
    float4 v1 = in4[threadIdx.x + 256];

    float m = fmaxf(fmaxf(fmaxf(v0.x, v0.y), fmaxf(v0.z, v0.w)),
                    fmaxf(fmaxf(v1.x, v1.y), fmaxf(v1.z, v1.w)));
    #pragma unroll
    for (int off = 32; off > 0; off >>= 1) m = fmaxf(m, __shfl_xor(m, off));

    __shared__ float red[4];
    if ((threadIdx.x & 63) == 0) red[threadIdx.x >> 6] = m;
    __syncthreads();
    m = fmaxf(fmaxf(red[0], red[1]), fmaxf(red[2], red[3]));
    __syncthreads();

    float e[8];
    e[0] = expf(v0.x - m); e[1] = expf(v0.y - m);
    e[2] = expf(v0.z - m); e[3] = expf(v0.w - m);
    e[4] = expf(v1.x - m); e[5] = expf(v1.y - m);
    e[6] = expf(v1.z - m); e[7] = expf(v1.w - m);

    float s = e[0] + e[1] + e[2] + e[3] + e[4] + e[5] + e[6] + e[7];
    #pragma unroll
    for (int off = 32; off > 0; off >>= 1) s += __shfl_xor(s, off);
    if ((threadIdx.x & 63) == 0) red[threadIdx.x >> 6] = s;
    __syncthreads();
    s = red[0] + red[1] + red[2] + red[3];

    float inv = 1.0f / s;
    out4[threadIdx.x]       = make_float4(e[0] * inv, e[1] * inv, e[2] * inv, e[3] * inv);
    out4[threadIdx.x + 256] = make_float4(e[4] * inv, e[5] * inv, e[6] * inv, e[7] * inv);
}

__global__ void copy_vec(const float* __restrict__ src, float* __restrict__ dst, int n)
{
    int i = blockIdx.x * blockDim.x + threadIdx.x;
    if (i < n) dst[i] = src[i];
}

// ---------------------------------------------------------------------------
extern "C" void kernel_launch(void* const* d_in, const int* in_sizes, int n_in,
                              void* d_out, int out_size, void* d_ws, size_t ws_size,
                              hipStream_t stream)
{
    const float* x  = (const float*)d_in[0];
    const float* Wh = (const float*)d_in[1];
    const float* Wx = (const float*)d_in[2];
    const float* Wy = (const float*)d_in[3];
    const float* Bh = (const float*)d_in[4];
    const float* By = (const float*)d_in[5];

    float* out    = (float*)d_out;
    float* hfinal = out;
    float* hs     = out + HDIM;          // [T][H], later overwritten by probs

    // ws layout: xpT [H][T] (64MB) | hbuf 32KB | cnt 512B | pub 4 | done 4 | lbuf 64MB
    char*  base = (char*)d_ws;
    float* xpT  = (float*)base;
    u64*   hbuf = (u64*)(base + (size_t)T_SEQ * HDIM * 4);
    u32*   cnt  = (u32*)((char*)hbuf + 2 * HDIM * sizeof(u64));
    u32*   pub  = cnt + 128;
    u32*   done = pub + 1;
    float* lbuf = (float*)(base + (size_t)T_SEQ * HDIM * 4 + 65536);

    size_t need_fuse3 = (size_t)T_SEQ * HDIM * 4 * 2 + 65536 + (size_t)T_SEQ * EDIM * 4 - (size_t)T_SEQ * HDIM * 4;
    // = xpT + 64KB ctrl + lbuf
    need_fuse3 = (size_t)T_SEQ * HDIM * 4 + 65536 + (size_t)T_SEQ * EDIM * 4;
    int fuse3 = (ws_size >= need_fuse3) ? 1 : 0;

    // zero sync state (hbuf tags + counters) — replay-safe
    hipMemsetAsync(hbuf, 0, 2 * HDIM * sizeof(u64) + 1024, stream);

    const float* x_c = x; const float* Wh_c = Wh; const float* Wx_c = Wx;
    const float* Wy_c = Wy; const float* Bh_c = Bh; const float* By_c = By;
    void* args[] = {(void*)&x_c, (void*)&Wh_c, (void*)&Wx_c, (void*)&Wy_c,
                    (void*)&Bh_c, (void*)&By_c,
                    (void*)&xpT, (void*)&hs, (void*)&hbuf,
                    (void*)&cnt, (void*)&pub, (void*)&done,
                    (void*)&lbuf, (void*)&fuse3};
    hipLaunchCooperativeKernel((void*)rnn_fused, dim3(RBLK + NWORK), dim3(512),
                               args, 0, stream);

    float* logits = fuse3 ? lbuf : xpT;
    if (!fuse3) {
        gemm_nt_bias<<<dim3(EDIM / 64, T_SEQ / 64), 256, 0, stream>>>(
            hs, Wy, By, logits, T_SEQ, EDIM, HDIM);
    }

    copy_vec<<<dim3(HDIM / 256), 256, 0, stream>>>(
        hs + (size_t)(T_SEQ - 1) * HDIM, hfinal, HDIM);

    softmax_rows<<<dim3(T_SEQ), 256, 0, stream>>>(logits, hs);
}

// Round 13
// 14335.394 us; speedup vs baseline: 1.6736x; 1.5671x over previous
//
#include <hip/hip_runtime.h>

#define T_SEQ 8192
#define HDIM  2048
#define EDIM  2048
#define RBLK  64                      // recurrence blocks
#define ROWS_PER_BLK (HDIM / RBLK)    // 32 rows/block, 4 rows/wave

typedef unsigned long long u64;
typedef __attribute__((ext_vector_type(4))) unsigned int u32x4;
typedef __attribute__((ext_vector_type(4))) float f32x4;

// two 16B agent-coherent loads + full drain (R9 proven poll)
__device__ inline void poll_pair(const u64* p0, const u64* p1, u32x4& a, u32x4& b) {
    asm volatile("global_load_dwordx4 %0, %2, off sc1\n\t"
                 "global_load_dwordx4 %1, %3, off sc1\n\t"
                 "s_waitcnt vmcnt(0)"
                 : "=v"(a), "=v"(b) : "v"(p0), "v"(p1) : "memory");
}

// Non-rematerializable 16B load: result MUST live in registers (asm output).
__device__ inline f32x4 ld_w16(const float* p) {
    f32x4 r;
    asm volatile("global_load_dwordx4 %0, %1, off" : "=v"(r) : "v"(p));
    return r;
}

// tanh via e^{2z}: clamp +-15, exp2, rcp (validated R8/R9: absmax unchanged)
__device__ inline float fast_tanh(float z) {
    float zc = fminf(fmaxf(z, -15.f), 15.f);
    float zs = zc * 2.88539008177792681f;   // 2*log2(e)
    float ez; asm("v_exp_f32 %0, %1" : "=v"(ez) : "v"(zs));
    float rc; float ezp = ez + 1.f;
    asm("v_rcp_f32 %0, %1" : "=v"(rc) : "v"(ezp));
    return (ez - 1.f) * rc;
}

// ---------------------------------------------------------------------------
// 128x128-tile GEMM (NT): C[m][n] = sum_k A[m][k]*B[n][k] + bias[n]
// BK=16, 256 threads, 8x8 microtile: 0.5 B/FLOP LDS traffic (2x less than
// the old 64^2 kernel, which was LDS-BW-bound at ~76 TF).
// K-order identical to old kernel -> bit-identical results.
// ---------------------------------------------------------------------------
__global__ __launch_bounds__(256) void gemm128_nt_bias(
    const float* __restrict__ A, const float* __restrict__ B,
    const float* __restrict__ bias, float* __restrict__ C,
    int M, int N, int K)
{
    __shared__ float As[16][128 + 4];
    __shared__ float Bs[16][128 + 4];

    const int tid = threadIdx.x;
    const int tx = tid & 15;           // n
    const int ty = tid >> 4;           // m
    const int m0 = blockIdx.y * 128;
    const int n0 = blockIdx.x * 128;

    float acc[8][8] = {};

    for (int kk = 0; kk < K; kk += 16) {
        #pragma unroll
        for (int p = 0; p < 2; ++p) {
            int idx = p * 256 + tid;        // 0..511
            int r  = idx >> 2;              // 0..127
            int cb = (idx & 3) * 4;         // 0,4,8,12
            float4 va = *(const float4*)&A[(size_t)(m0 + r) * K + kk + cb];
            As[cb + 0][r] = va.x; As[cb + 1][r] = va.y;
            As[cb + 2][r] = va.z; As[cb + 3][r] = va.w;
            float4 vb = *(const float4*)&B[(size_t)(n0 + r) * K + kk + cb];
            Bs[cb + 0][r] = vb.x; Bs[cb + 1][r] = vb.y;
            Bs[cb + 2][r] = vb.z; Bs[cb + 3][r] = vb.w;
        }
        __syncthreads();
        #pragma unroll
        for (int k = 0; k < 16; ++k) {
            float4 a0 = *(const float4*)&As[k][ty * 8];
            float4 a1 = *(const float4*)&As[k][ty * 8 + 4];
            float4 b0 = *(const float4*)&Bs[k][tx * 8];
            float4 b1 = *(const float4*)&Bs[k][tx * 8 + 4];
            float av[8] = {a0.x, a0.y, a0.z, a0.w, a1.x, a1.y, a1.z, a1.w};
            float bv[8] = {b0.x, b0.y, b0.z, b0.w, b1.x, b1.y, b1.z, b1.w};
            #pragma unroll
            for (int i = 0; i < 8; ++i)
                #pragma unroll
                for (int j = 0; j < 8; ++j)
                    acc[i][j] = fmaf(av[i], bv[j], acc[i][j]);
        }
        __syncthreads();
    }

    float4 bb0 = *(const float4*)&bias[n0 + tx * 8];
    float4 bb1 = *(const float4*)&bias[n0 + tx * 8 + 4];
    float bv[8] = {bb0.x, bb0.y, bb0.z, bb0.w, bb1.x, bb1.y, bb1.z, bb1.w};
    #pragma unroll
    for (int i = 0; i < 8; ++i) {
        float4 o0, o1;
        o0.x = acc[i][0] + bv[0]; o0.y = acc[i][1] + bv[1];
        o0.z = acc[i][2] + bv[2]; o0.w = acc[i][3] + bv[3];
        o1.x = acc[i][4] + bv[4]; o1.y = acc[i][5] + bv[5];
        o1.z = acc[i][6] + bv[6]; o1.w = acc[i][7] + bv[7];
        float* cp = &C[(size_t)(m0 + ty * 8 + i) * N + n0 + tx * 8];
        *(float4*)cp = o0;
        *(float4*)(cp + 4) = o1;
    }
}

// ---------------------------------------------------------------------------
// Same 128x128 GEMM, TRANSPOSED output: Ct[n][m] (xpT: 16 steps per line).
// ---------------------------------------------------------------------------
__global__ __launch_bounds__(256) void gemm128_nt_bias_tc(
    const float* __restrict__ A, const float* __restrict__ B,
    const float* __restrict__ bias, float* __restrict__ Ct,
    int M, int N, int K)
{
    __shared__ float As[16][128 + 4];
    __shared__ float Bs[16][128 + 4];

    const int tid = threadIdx.x;
    const int tx = tid & 15;           // n
    const int ty = tid >> 4;           // m
    const int m0 = blockIdx.y * 128;
    const int n0 = blockIdx.x * 128;

    float acc[8][8] = {};

    for (int kk = 0; kk < K; kk += 16) {
        #pragma unroll
        for (int p = 0; p < 2; ++p) {
            int idx = p * 256 + tid;
            int r  = idx >> 2;
            int cb = (idx & 3) * 4;
            float4 va = *(const float4*)&A[(size_t)(m0 + r) * K + kk + cb];
            As[cb + 0][r] = va.x; As[cb + 1][r] = va.y;
            As[cb + 2][r] = va.z; As[cb + 3][r] = va.w;
            float4 vb = *(const float4*)&B[(size_t)(n0 + r) * K + kk + cb];
            Bs[cb + 0][r] = vb.x; Bs[cb + 1][r] = vb.y;
            Bs[cb + 2][r] = vb.z; Bs[cb + 3][r] = vb.w;
        }
        __syncthreads();
        #pragma unroll
        for (int k = 0; k < 16; ++k) {
            float4 a0 = *(const float4*)&As[k][ty * 8];
            float4 a1 = *(const float4*)&As[k][ty * 8 + 4];
            float4 b0 = *(const float4*)&Bs[k][tx * 8];
            float4 b1 = *(const float4*)&Bs[k][tx * 8 + 4];
            float av[8] = {a0.x, a0.y, a0.z, a0.w, a1.x, a1.y, a1.z, a1.w};
            float bv[8] = {b0.x, b0.y, b0.z, b0.w, b1.x, b1.y, b1.z, b1.w};
            #pragma unroll
            for (int i = 0; i < 8; ++i)
                #pragma unroll
                for (int j = 0; j < 8; ++j)
                    acc[i][j] = fmaf(av[i], bv[j], acc[i][j]);
        }
        __syncthreads();
    }

    // acc[i][j]: m = m0+ty*8+i, n = n0+tx*8+j. Write m-contiguous float4s.
    #pragma unroll
    for (int j = 0; j < 8; ++j) {
        float bb = bias[n0 + tx * 8 + j];
        float4 o0, o1;
        o0.x = acc[0][j] + bb; o0.y = acc[1][j] + bb;
        o0.z = acc[2][j] + bb; o0.w = acc[3][j] + bb;
        o1.x = acc[4][j] + bb; o1.y = acc[5][j] + bb;
        o1.z = acc[6][j] + bb; o1.w = acc[7][j] + bb;
        float* cp = &Ct[(size_t)(n0 + tx * 8 + j) * M + m0 + ty * 8];
        *(float4*)cp = o0;
        *(float4*)(cp + 4) = o1;
    }
}

// ---------------------------------------------------------------------------
// Recurrence — byte-identical to R9 (proven best: 12.75 ms).
// 64 blocks x 512 threads; wave w owns rows b*32+w*4..+3; W_h in 128
// asm-loaded registers/lane. Sync: hbuf[2][HDIM] u64 (tag<<32|f32bits), tag
// travels with data; readers poll 16B sc1 loads; writers relaxed agent-scope
// atomic exchange. Overwrite of the recycled buffer is safe: a wave's tag-t
// store value-depends on ALL its step-(t-1) loads, and poll success requires
// all 2048 tag-t words.
// ---------------------------------------------------------------------------
__global__ __launch_bounds__(512, 1) void rnn_recurrence(
    const float* __restrict__ Wh, const float* __restrict__ xpT,
    float* __restrict__ Hs, u64* __restrict__ hbuf, int T)
{
    const int tid  = threadIdx.x;
    const int lane = tid & 63;
    const int wid  = tid >> 6;                              // 0..7
    const int r0   = blockIdx.x * ROWS_PER_BLK + wid * 4;   // wave's first row

    const float* wr0 = Wh + (size_t)(r0 + 0) * HDIM + lane * 4;
    const float* wr1 = Wh + (size_t)(r0 + 1) * HDIM + lane * 4;
    const float* wr2 = Wh + (size_t)(r0 + 2) * HDIM + lane * 4;
    const float* wr3 = Wh + (size_t)(r0 + 3) * HDIM + lane * 4;

    f32x4 w00 = ld_w16(wr0 + 0*256), w01 = ld_w16(wr0 + 1*256), w02 = ld_w16(wr0 + 2*256), w03 = ld_w16(wr0 + 3*256);
    f32x4 w04 = ld_w16(wr0 + 4*256), w05 = ld_w16(wr0 + 5*256), w06 = ld_w16(wr0 + 6*256), w07 = ld_w16(wr0 + 7*256);
    f32x4 w10 = ld_w16(wr1 + 0*256), w11 = ld_w16(wr1 + 1*256), w12 = ld_w16(wr1 + 2*256), w13 = ld_w16(wr1 + 3*256);
    f32x4 w14 = ld_w16(wr1 + 4*256), w15 = ld_w16(wr1 + 5*256), w16 = ld_w16(wr1 + 6*256), w17 = ld_w16(wr1 + 7*256);
    f32x4 w20 = ld_w16(wr2 + 0*256), w21 = ld_w16(wr2 + 1*256), w22 = ld_w16(wr2 + 2*256), w23 = ld_w16(wr2 + 3*256);
    f32x4 w24 = ld_w16(wr2 + 4*256), w25 = ld_w16(wr2 + 5*256), w26 = ld_w16(wr2 + 6*256), w27 = ld_w16(wr2 + 7*256);
    f32x4 w30 = ld_w16(wr3 + 0*256), w31 = ld_w16(wr3 + 1*256), w32 = ld_w16(wr3 + 2*256), w33 = ld_w16(wr3 + 3*256);
    f32x4 w34 = ld_w16(wr3 + 4*256), w35 = ld_w16(wr3 + 5*256), w36 = ld_w16(wr3 + 6*256), w37 = ld_w16(wr3 + 7*256);
    asm volatile("s_waitcnt vmcnt(0)" ::: "memory");

    __shared__ float hsm[HDIM];

    for (int t = 0; t < T; ++t) {
        float xq = 0.f;
        if (lane < 4) xq = xpT[(size_t)(r0 + lane) * T + t];

        float sv = 0.f;
        if (t > 0) {
            const u64* hb = hbuf + (size_t)(t & 1) * HDIM;
            const unsigned tg = (unsigned)t;
            const u64* p0 = hb + 2 * tid;
            const u64* p1 = hb + 1024 + 2 * tid;

            u32x4 a, b;
            poll_pair(p0, p1, a, b);
            while ((a.y != tg) | (a.w != tg) | (b.y != tg) | (b.w != tg))
                poll_pair(p0, p1, a, b);

            ((float2*)hsm)[tid] =
                make_float2(__uint_as_float(a.x), __uint_as_float(a.z));
            ((float2*)hsm)[tid + 512] =
                make_float2(__uint_as_float(b.x), __uint_as_float(b.z));
            __syncthreads();

            float s0 = 0.f, s1 = 0.f, s2 = 0.f, s3 = 0.f;
            #define RNN_STEP(IDX, WA, WB, WC, WD)                                   \
            {   float4 h4 = ((const float4*)hsm)[(IDX) * 64 + lane];                \
                s0 = fmaf(WA.x, h4.x, s0); s0 = fmaf(WA.y, h4.y, s0);               \
                s0 = fmaf(WA.z, h4.z, s0); s0 = fmaf(WA.w, h4.w, s0);               \
                s1 = fmaf(WB.x, h4.x, s1); s1 = fmaf(WB.y, h4.y, s1);               \
                s1 = fmaf(WB.z, h4.z, s1); s1 = fmaf(WB.w, h4.w, s1);               \
                s2 = fmaf(WC.x, h4.x, s2); s2 = fmaf(WC.y, h4.y, s2);               \
                s2 = fmaf(WC.z, h4.z, s2); s2 = fmaf(WC.w, h4.w, s2);               \
                s3 = fmaf(WD.x, h4.x, s3); s3 = fmaf(WD.y, h4.y, s3);               \
                s3 = fmaf(WD.z, h4.z, s3); s3 = fmaf(WD.w, h4.w, s3); }
            RNN_STEP(0, w00, w10, w20, w30)
            RNN_STEP(1, w01, w11, w21, w31)
            RNN_STEP(2, w02, w12, w22, w32)
            RNN_STEP(3, w03, w13, w23, w33)
            RNN_STEP(4, w04, w14, w24, w34)
            RNN_STEP(5, w05, w15, w25, w35)
            RNN_STEP(6, w06, w16, w26, w36)
            RNN_STEP(7, w07, w17, w27, w37)
            #undef RNN_STEP

            float fa = (lane & 1) ? s1 : s0;
            float fb = (lane & 1) ? s0 : s1;
            fa += __shfl_xor(fb, 1);
            float fc = (lane & 1) ? s3 : s2;
            float fd = (lane & 1) ? s2 : s3;
            fc += __shfl_xor(fd, 1);
            float fe = (lane & 2) ? fc : fa;
            float ff = (lane & 2) ? fa : fc;
            fe += __shfl_xor(ff, 2);
            #pragma unroll
            for (int off = 4; off < 64; off <<= 1) fe += __shfl_xor(fe, off);
            sv = fe;
        }

        if (lane < 4) {
            float hn = fast_tanh(sv + xq);
            u64 pk = ((u64)(unsigned)(t + 1) << 32) | (u64)__float_as_uint(hn);
            (void)__hip_atomic_exchange(
                &hbuf[(size_t)((t + 1) & 1) * HDIM + r0 + lane], pk,
                __ATOMIC_RELAXED, __HIP_MEMORY_SCOPE_AGENT);
            Hs[(size_t)t * HDIM + r0 + lane] = hn;
        }
    }
}

// ---------------------------------------------------------------------------
// Row softmax over EDIM=2048: one block (256 threads) per row.
// ---------------------------------------------------------------------------
__global__ __launch_bounds__(256) void softmax_rows(
    const float* __restrict__ logits, float* __restrict__ out)
{
    const int row = blockIdx.x;
    const float4* in4 = (const float4*)(logits + (size_t)row * EDIM);
    float4* out4 = (float4*)(out + (size_t)row * EDIM);

    float4 v0 = in4[threadIdx.x];
    float4 v1 = in4[threadIdx.x + 256];

    float m = fmaxf(fmaxf(fmaxf(v0.x, v0.y), fmaxf(v0.z, v0.w)),
                    fmaxf(fmaxf(v1.x, v1.y), fmaxf(v1.z, v1.w)));
    #pragma unroll
    for (int off = 32; off > 0; off >>= 1) m = fmaxf(m, __shfl_xor(m, off));

    __shared__ float red[4];
    if ((threadIdx.x & 63) == 0) red[threadIdx.x >> 6] = m;
    __syncthreads();
    m = fmaxf(fmaxf(red[0], red[1]), fmaxf(red[2], red[3]));
    __syncthreads();

    float e[8];
    e[0] = expf(v0.x - m); e[1] = expf(v0.y - m);
    e[2] = expf(v0.z - m); e[3] = expf(v0.w - m);
    e[4] = expf(v1.x - m); e[5] = expf(v1.y - m);
    e[6] = expf(v1.z - m); e[7] = expf(v1.w - m);

    float s = e[0] + e[1] + e[2] + e[3] + e[4] + e[5] + e[6] + e[7];
    #pragma unroll
    for (int off = 32; off > 0; off >>= 1) s += __shfl_xor(s, off);
    if ((threadIdx.x & 63) == 0) red[threadIdx.x >> 6] = s;
    __syncthreads();
    s = red[0] + red[1] + red[2] + red[3];

    float inv = 1.0f / s;
    out4[threadIdx.x]       = make_float4(e[0] * inv, e[1] * inv, e[2] * inv, e[3] * inv);
    out4[threadIdx.x + 256] = make_float4(e[4] * inv, e[5] * inv, e[6] * inv, e[7] * inv);
}

__global__ void copy_vec(const float* __restrict__ src, float* __restrict__ dst, int n)
{
    int i = blockIdx.x * blockDim.x + threadIdx.x;
    if (i < n) dst[i] = src[i];
}

// ---------------------------------------------------------------------------
extern "C" void kernel_launch(void* const* d_in, const int* in_sizes, int n_in,
                              void* d_out, int out_size, void* d_ws, size_t ws_size,
                              hipStream_t stream)
{
    const float* x  = (const float*)d_in[0];   // [T_SEQ][EDIM]
    const float* Wh = (const float*)d_in[1];   // [HDIM][HDIM]
    const float* Wx = (const float*)d_in[2];   // [HDIM][EDIM]
    const float* Wy = (const float*)d_in[3];   // [EDIM][HDIM]
    const float* Bh = (const float*)d_in[4];   // [HDIM]
    const float* By = (const float*)d_in[5];   // [EDIM]

    float* out    = (float*)d_out;
    float* hfinal = out;                 // [HDIM]
    float* hs     = out + HDIM;          // [T_SEQ][HDIM]: holds hs, then probs

    float* xpT  = (float*)d_ws;                                   // [HDIM][T_SEQ]
    u64*   hbuf = (u64*)((char*)d_ws + (size_t)T_SEQ * HDIM * 4); // [2][HDIM]
    float* logits = xpT;                 // reuse (xpT dead after recurrence)

    // clear tagged h buffers so replays never see stale tags
    hipMemsetAsync(hbuf, 0, 2 * HDIM * sizeof(u64), stream);

    // Phase 1: xpT = (x @ Wx^T + Bh)^T   -> [HDIM][T_SEQ]
    gemm128_nt_bias_tc<<<dim3(HDIM / 128, T_SEQ / 128), 256, 0, stream>>>(
        x, Wx, Bh, xpT, T_SEQ, HDIM, EDIM);

    // Phase 2: recurrence — cooperative launch only to guarantee co-residency
    int T = T_SEQ;
    const float* xpT_c = xpT;
    void* args[] = {(void*)&Wh, (void*)&xpT_c, (void*)&hs, (void*)&hbuf, (void*)&T};
    hipLaunchCooperativeKernel((void*)rnn_recurrence, dim3(RBLK), dim3(512),
                               args, 0, stream);

    // Phase 3: logits = hs @ Wy^T + By   (normal [T][E] layout)
    gemm128_nt_bias<<<dim3(EDIM / 128, T_SEQ / 128), 256, 0, stream>>>(
        hs, Wy, By, logits, T_SEQ, EDIM, HDIM);

    // Phase 4: h_final = hs[T-1] (before softmax overwrites hs region)
    copy_vec<<<dim3(HDIM / 256), 256, 0, stream>>>(
        hs + (size_t)(T_SEQ - 1) * HDIM, hfinal, HDIM);

    // Phase 5: softmax rows: logits (ws) -> output region of d_out
    softmax_rows<<<dim3(T_SEQ), 256, 0, stream>>>(logits, hs);
}